// Round 1
// baseline (419.593 us; speedup 1.0000x reference)
//
#include <hip/hip_runtime.h>

// MeshConv: out[e][o] = b[o] + sum_k combined[e][k] * W[o][k]
// combined = [x (32) | (a0+a1)+(b0+b1) (32) | |a0-a1|+|b0-b1| (32) |
//             |(a0+a1)-(b0+b1)| (32) | ||a0-a1|-|b0-b1|| (32)]  -> K=160
// Strategy: gather+descriptor in fp32, round once to bf16, MFMA 16x16x32 bf16,
// fp32 accumulate, bias in fp32. Persistent blocks amortize W->bf16 conversion.

typedef __bf16 bf16_t;
typedef __bf16 bf16x8 __attribute__((ext_vector_type(8)));
typedef float  f32x4  __attribute__((ext_vector_type(4)));

#define EC      1000000
#define CCH     32
#define OUTD    64
#define KD      160          // 5*CCH
#define MT      64           // elements per tile
#define LSTR    168          // LDS row stride in bf16 (padded: 168*2=336B, 16B-aligned, bank-rotating)
#define NTILES  (EC / MT)    // 15625 exactly

__global__ __launch_bounds__(256)
void meshconv_kernel(const float* __restrict__ x,
                     const int*   __restrict__ nbr,
                     const float* __restrict__ W,
                     const float* __restrict__ bias,
                     float*       __restrict__ out)
{
    __shared__ bf16_t w_lds[OUTD * LSTR];   // 21 KB
    __shared__ bf16_t c_lds[MT * LSTR];     // 21 KB  -> 43 KB total, 3 blocks/CU

    const int tid  = threadIdx.x;
    const int wave = tid >> 6;
    const int lane = tid & 63;
    const int col  = lane & 15;   // A-row / B-col / C-col index within 16-tile
    const int quad = lane >> 4;   // k0 = quad*8 for A/B frags; C rows = quad*4+r

    // ---- one-time: W (64x160 f32, row-major) -> bf16 LDS ----
    for (int i = tid; i < (OUTD * KD) / 4; i += 256) {
        const int row = i / 40;              // 40 float4 per row
        const int c4  = (i - row * 40) * 4;
        f32x4 wv = ((const f32x4*)W)[i];
        bf16_t* d = &w_lds[row * LSTR + c4];
        d[0] = (bf16_t)wv[0]; d[1] = (bf16_t)wv[1];
        d[2] = (bf16_t)wv[2]; d[3] = (bf16_t)wv[3];
    }

    float bv[4];
#pragma unroll
    for (int tn = 0; tn < 4; ++tn) bv[tn] = bias[tn * 16 + col];

    const int e_loc = tid >> 2;  // 0..63: element within tile (4 threads/element)
    const int part  = tid & 3;   // channels [part*8, part*8+8)

    for (int tile = blockIdx.x; tile < NTILES; tile += (int)gridDim.x) {
        const int e = tile * MT + e_loc;

        // ---- Phase 1: gather 5 rows, build descriptor, store bf16 to LDS ----
        const int4 nb = ((const int4*)nbr)[e];
        const float m0 = nb.x < 0 ? 0.f : 1.f;
        const float m1 = nb.y < 0 ? 0.f : 1.f;
        const float m2 = nb.z < 0 ? 0.f : 1.f;
        const float m3 = nb.w < 0 ? 0.f : 1.f;
        const int i0 = nb.x < 0 ? 0 : nb.x;
        const int i1 = nb.y < 0 ? 0 : nb.y;
        const int i2 = nb.z < 0 ? 0 : nb.z;
        const int i3 = nb.w < 0 ? 0 : nb.w;

        const f32x4* px  = (const f32x4*)(x + (size_t)e  * CCH) + part * 2;
        const f32x4* pa0 = (const f32x4*)(x + (size_t)i0 * CCH) + part * 2;
        const f32x4* pa1 = (const f32x4*)(x + (size_t)i1 * CCH) + part * 2;
        const f32x4* pb0 = (const f32x4*)(x + (size_t)i2 * CCH) + part * 2;
        const f32x4* pb1 = (const f32x4*)(x + (size_t)i3 * CCH) + part * 2;

        f32x4 xv[2], a0[2], a1[2], b0[2], b1[2];
#pragma unroll
        for (int h = 0; h < 2; ++h) {
            xv[h] = px[h];
            a0[h] = pa0[h] * m0;
            a1[h] = pa1[h] * m1;
            b0[h] = pb0[h] * m2;
            b1[h] = pb1[h] * m3;
        }

        bf16x8 vx, v1, v2, v3, v4;
#pragma unroll
        for (int h = 0; h < 2; ++h) {
#pragma unroll
            for (int j = 0; j < 4; ++j) {
                const int jj = h * 4 + j;
                const float sa = a0[h][j] + a1[h][j];
                const float da = fabsf(a0[h][j] - a1[h][j]);
                const float sb = b0[h][j] + b1[h][j];
                const float db = fabsf(b0[h][j] - b1[h][j]);
                vx[jj] = (bf16_t)xv[h][j];
                v1[jj] = (bf16_t)(sa + sb);
                v2[jj] = (bf16_t)(da + db);
                v3[jj] = (bf16_t)fabsf(sa - sb);
                v4[jj] = (bf16_t)fabsf(da - db);
            }
        }

        bf16_t* rowp = &c_lds[e_loc * LSTR + part * 8];
        *(bf16x8*)(rowp +   0) = vx;
        *(bf16x8*)(rowp +  32) = v1;
        *(bf16x8*)(rowp +  64) = v2;
        *(bf16x8*)(rowp +  96) = v3;
        *(bf16x8*)(rowp + 128) = v4;

        __syncthreads();

        // ---- Phase 2: MFMA. Each wave: 16 rows x 64 cols, K=160 ----
        f32x4 acc[4] = {{0.f,0.f,0.f,0.f},{0.f,0.f,0.f,0.f},
                        {0.f,0.f,0.f,0.f},{0.f,0.f,0.f,0.f}};
#pragma unroll
        for (int ks = 0; ks < 5; ++ks) {
            const bf16x8 af = *(const bf16x8*)&c_lds[(wave * 16 + col) * LSTR + ks * 32 + quad * 8];
#pragma unroll
            for (int tn = 0; tn < 4; ++tn) {
                const bf16x8 bfr = *(const bf16x8*)&w_lds[(tn * 16 + col) * LSTR + ks * 32 + quad * 8];
                acc[tn] = __builtin_amdgcn_mfma_f32_16x16x32_bf16(af, bfr, acc[tn], 0, 0, 0);
            }
        }

        // ---- Epilogue: C/D layout col=lane&15, row=quad*4+reg ----
#pragma unroll
        for (int tn = 0; tn < 4; ++tn) {
            float* op = out + (size_t)(tile * MT + wave * 16 + quad * 4) * OUTD + tn * 16 + col;
#pragma unroll
            for (int r = 0; r < 4; ++r)
                op[(size_t)r * OUTD] = acc[tn][r] + bv[tn];
        }

        __syncthreads();  // protect c_lds before next iteration overwrites
    }
}

extern "C" void kernel_launch(void* const* d_in, const int* in_sizes, int n_in,
                              void* d_out, int out_size, void* d_ws, size_t ws_size,
                              hipStream_t stream) {
    const float* x    = (const float*)d_in[0];
    const int*   nbr  = (const int*)d_in[1];
    const float* W    = (const float*)d_in[2];
    const float* bias = (const float*)d_in[3];
    float* out = (float*)d_out;
    // 768 blocks = 256 CUs x 3 blocks/CU (43 KB LDS each); grid-stride over 15625 tiles
    meshconv_kernel<<<dim3(768), dim3(256), 0, stream>>>(x, nbr, W, bias, out);
}